// Round 2
// baseline (1073.881 us; speedup 1.0000x reference)
//
#include <hip/hip_runtime.h>
#include <hip/hip_bf16.h>

#define N_ 4
#define C_ 512
#define CI_ 256
#define S_ 6272
#define EPS_ 1e-5f

typedef __attribute__((ext_vector_type(8))) __bf16 bf16x8;
typedef __attribute__((ext_vector_type(4))) __bf16 bf16x4;
typedef __attribute__((ext_vector_type(4))) float f32x4;

#define MFMA(a, b, c) __builtin_amdgcn_mfma_f32_16x16x32_bf16(a, b, c, 0, 0, 0)

// ---------------- Kernel 1: QKV projections ----------------
// Orientation: M = ci, N = s, K = c.  Outputs:
//   theta[n][s][ci], phi[n][s][ci] (bf16)   gT[n][ci][s] (bf16)
__global__ __launch_bounds__(256) void qkv_kernel(
    const float* __restrict__ x,
    const float* __restrict__ w_theta, const float* __restrict__ b_theta,
    const float* __restrict__ w_phi,   const float* __restrict__ b_phi,
    const float* __restrict__ w_g,     const float* __restrict__ b_g,
    __bf16* __restrict__ theta, __bf16* __restrict__ phi, __bf16* __restrict__ gT)
{
    const int s0  = blockIdx.x * 64;
    const int ci0 = blockIdx.y * 64;
    const int n   = blockIdx.z;
    const int tid = threadIdx.x;
    const int wave = tid >> 6, lane = tid & 63;
    const int m16 = lane & 15, quad = lane >> 4;

    __shared__ __bf16 xT[64][40];  // [s-local][c-local(32)], pad->40

    const float* wptr[3] = {w_theta, w_phi, w_g};

    f32x4 acc[3][4];
    #pragma unroll
    for (int j = 0; j < 3; ++j)
        #pragma unroll
        for (int ss = 0; ss < 4; ++ss) acc[j][ss] = f32x4{0.f, 0.f, 0.f, 0.f};

    const int ci_row = ci0 + wave * 16 + m16;  // A-frag row (M index)

    for (int kc = 0; kc < 16; ++kc) {
        __syncthreads();  // protect previous iteration's xT reads
        #pragma unroll
        for (int it = 0; it < 8; ++it) {
            int idx = it * 256 + tid;
            int cc = idx >> 6, ss = idx & 63;
            float v = x[((size_t)n * C_ + (size_t)kc * 32 + cc) * S_ + s0 + ss];
            xT[ss][cc] = (__bf16)v;
        }
        __syncthreads();

        bf16x8 afr[3];
        #pragma unroll
        for (int j = 0; j < 3; ++j) {
            const float* wp = wptr[j] + (size_t)ci_row * C_ + kc * 32 + quad * 8;
            bf16x8 t;
            #pragma unroll
            for (int e = 0; e < 8; ++e) t[e] = (__bf16)wp[e];
            afr[j] = t;
        }
        #pragma unroll
        for (int ss = 0; ss < 4; ++ss) {
            bf16x8 bfr = *(const bf16x8*)&xT[ss * 16 + m16][quad * 8];
            #pragma unroll
            for (int j = 0; j < 3; ++j)
                acc[j][ss] = MFMA(afr[j], bfr, acc[j][ss]);
        }
    }

    const int ci_base = ci0 + wave * 16 + quad * 4;
    float bth[4], bph[4], bgg[4];
    #pragma unroll
    for (int r = 0; r < 4; ++r) {
        bth[r] = b_theta[ci_base + r];
        bph[r] = b_phi[ci_base + r];
        bgg[r] = b_g[ci_base + r];
    }
    #pragma unroll
    for (int ss = 0; ss < 4; ++ss) {
        int s = s0 + ss * 16 + m16;
        bf16x4 tv, pv;
        #pragma unroll
        for (int r = 0; r < 4; ++r) {
            tv[r] = (__bf16)(acc[0][ss][r] + bth[r]);
            pv[r] = (__bf16)(acc[1][ss][r] + bph[r]);
        }
        *(bf16x4*)&theta[((size_t)n * S_ + s) * CI_ + ci_base] = tv;
        *(bf16x4*)&phi[((size_t)n * S_ + s) * CI_ + ci_base]   = pv;
        #pragma unroll
        for (int r = 0; r < 4; ++r)
            gT[((size_t)n * CI_ + ci_base + r) * S_ + s] = (__bf16)(acc[2][ss][r] + bgg[r]);
    }
}

// ---------------- Kernel 2: flash attention (wave-split K/ci, reg-resident Q) ----------------
// Block: 64 queries, 4 waves.  kt loop over 98 key-tiles of 64.
// QK: wave w owns keys [p0+16w, p0+16w+16), computes scores^T for all 64 q.
//     A-frags (K) loaded DIRECT from global phi (16B/lane contiguous, L2-resident).
//     B-frags (Q) register-resident for the whole kernel (128 VGPR).
// Softmax: no max subtraction (scores bounded ~|1.2|); P to LDS; per-lane Σexp.
// PV: wave w owns ci [64w, 64w+64); A-frags (V) direct from global gT; B (P) from LDS.
// Cross-wave l-reduction once at the end.
__global__ __launch_bounds__(256) void attn_kernel(
    const __bf16* __restrict__ theta, const __bf16* __restrict__ phi,
    const __bf16* __restrict__ gT, __bf16* __restrict__ O)
{
    const int q0 = blockIdx.x * 64;
    const int n  = blockIdx.y;
    const int tid = threadIdx.x;
    const int w = tid >> 6, lane = tid & 63;
    const int m16 = lane & 15, quad = lane >> 4;

    __shared__ __bf16 p_lds[64][72];   // [q][key], pad 64->72
    __shared__ float  lsum[64][4];     // [q][wave]

    // Q B-frags: qreg[qfrag][kk]; lane holds B[n=qfrag*16+m16][k=kk*32+quad*8+j]
    bf16x8 qreg[4][8];
    #pragma unroll
    for (int qf = 0; qf < 4; ++qf) {
        const __bf16* qrow = theta + ((size_t)n * S_ + q0 + qf * 16 + m16) * CI_ + quad * 8;
        #pragma unroll
        for (int kk = 0; kk < 8; ++kk)
            qreg[qf][kk] = *(const bf16x8*)(qrow + kk * 32);
    }

    f32x4 o[4][4];  // [c][qf]  -> o[ci = w*64+c*16+quad*4+r][q = qf*16+m16]
    #pragma unroll
    for (int c = 0; c < 4; ++c)
        #pragma unroll
        for (int qf = 0; qf < 4; ++qf) o[c][qf] = f32x4{0.f, 0.f, 0.f, 0.f};
    float l_part[4] = {0.f, 0.f, 0.f, 0.f};

    // per-wave global bases (only p0 advances in the loop)
    const __bf16* kf_base = phi + ((size_t)n * S_ + w * 16 + m16) * CI_ + quad * 8;
    const __bf16* vf_base = gT + ((size_t)(n * CI_ + w * 64 + m16)) * S_ + quad * 8;

    for (int kt = 0; kt < 98; ++kt) {
        const int p0 = kt * 64;
        const __bf16* kp = kf_base + (size_t)p0 * CI_;

        // ---- QK^T: D[m=key-local 16][n=q 64] ----
        f32x4 sc[4];
        #pragma unroll
        for (int qf = 0; qf < 4; ++qf) sc[qf] = f32x4{0.f, 0.f, 0.f, 0.f};
        #pragma unroll
        for (int kk = 0; kk < 8; ++kk) {
            bf16x8 kf = *(const bf16x8*)(kp + kk * 32);
            #pragma unroll
            for (int qf = 0; qf < 4; ++qf)
                sc[qf] = MFMA(kf, qreg[qf][kk], sc[qf]);
        }

        // ---- exp (no max shift), accumulate l, pack P -> LDS [q][key] ----
        #pragma unroll
        for (int qf = 0; qf < 4; ++qf) {
            bf16x4 pk;
            float ls = 0.f;
            #pragma unroll
            for (int r = 0; r < 4; ++r) {
                float e = __expf(sc[qf][r] * 0.0625f);  // * ci^-0.5
                ls += e;
                pk[r] = (__bf16)e;
            }
            l_part[qf] += ls;
            // lane holds keys w*16+quad*4+r, q = qf*16+m16
            *(bf16x4*)&p_lds[qf * 16 + m16][w * 16 + quad * 4] = pk;
        }
        __syncthreads();

        // ---- PV: D[m=ci-local 64 per wave][n=q 64] ----
        #pragma unroll
        for (int kk2 = 0; kk2 < 2; ++kk2) {
            bf16x8 pf[4];
            #pragma unroll
            for (int qf = 0; qf < 4; ++qf)
                pf[qf] = *(const bf16x8*)&p_lds[qf * 16 + m16][kk2 * 32 + quad * 8];
            #pragma unroll
            for (int c = 0; c < 4; ++c) {
                bf16x8 vf = *(const bf16x8*)(vf_base + (size_t)(c * 16) * S_ + p0 + kk2 * 32);
                #pragma unroll
                for (int qf = 0; qf < 4; ++qf)
                    o[c][qf] = MFMA(vf, pf[qf], o[c][qf]);
            }
        }
        __syncthreads();  // protect p_lds WAR for next kt
    }

    // ---- cross-wave l reduction ----
    #pragma unroll
    for (int qf = 0; qf < 4; ++qf) {
        float l = l_part[qf];
        l += __shfl_xor(l, 16);
        l += __shfl_xor(l, 32);   // sum over quads (wave's key subset)
        if (quad == 0) lsum[qf * 16 + m16][w] = l;
    }
    __syncthreads();
    float invl[4];
    #pragma unroll
    for (int qf = 0; qf < 4; ++qf) {
        f32x4 v = *(const f32x4*)&lsum[qf * 16 + m16][0];
        invl[qf] = 1.0f / (v[0] + v[1] + v[2] + v[3]);
    }

    // ---- store O[n][s][ci] ----
    #pragma unroll
    for (int c = 0; c < 4; ++c)
        #pragma unroll
        for (int qf = 0; qf < 4; ++qf) {
            bf16x4 ov;
            #pragma unroll
            for (int r = 0; r < 4; ++r) ov[r] = (__bf16)(o[c][qf][r] * invl[qf]);
            *(bf16x4*)&O[((size_t)n * S_ + q0 + qf * 16 + m16) * CI_ + w * 64 + c * 16 + quad * 4] = ov;
        }
}

// ---------------- Kernel 3: w_out GEMM + BN partial stats ----------------
__global__ __launch_bounds__(256) void pgemm_kernel(
    const __bf16* __restrict__ O, const float* __restrict__ w_out,
    const float* __restrict__ b_out,
    __bf16* __restrict__ p, float* __restrict__ ssum, float* __restrict__ ssq)
{
    const int s0 = blockIdx.x * 64;
    const int c0 = blockIdx.y * 64;
    const int n  = blockIdx.z;
    const int tid = threadIdx.x;
    const int wave = tid >> 6, lane = tid & 63;
    const int m16 = lane & 15, quad = lane >> 4;

    __shared__ __bf16 o_lds[64][264];

    #pragma unroll
    for (int it = 0; it < 8; ++it) {
        int idx = it * 256 + tid;
        int row = idx >> 5, ch = idx & 31;
        *(uint4*)&o_lds[row][ch * 8] =
            *(const uint4*)&O[((size_t)n * S_ + s0 + row) * CI_ + ch * 8];
    }
    __syncthreads();

    const int c_row = c0 + wave * 16 + m16;
    bf16x8 af[8];
    #pragma unroll
    for (int kk = 0; kk < 8; ++kk) {
        const float* wp = w_out + (size_t)c_row * CI_ + kk * 32 + quad * 8;
        bf16x8 t;
        #pragma unroll
        for (int e = 0; e < 8; ++e) t[e] = (__bf16)wp[e];
        af[kk] = t;
    }
    f32x4 acc[4];
    #pragma unroll
    for (int ss = 0; ss < 4; ++ss) acc[ss] = f32x4{0.f, 0.f, 0.f, 0.f};
    #pragma unroll
    for (int ss = 0; ss < 4; ++ss)
        #pragma unroll
        for (int kk = 0; kk < 8; ++kk) {
            bf16x8 bfr = *(const bf16x8*)&o_lds[ss * 16 + m16][kk * 32 + quad * 8];
            acc[ss] = MFMA(af[kk], bfr, acc[ss]);
        }

    const int c_base = c0 + wave * 16 + quad * 4;
    float bo[4];
    #pragma unroll
    for (int r = 0; r < 4; ++r) bo[r] = b_out[c_base + r];
    float psum[4] = {0.f, 0.f, 0.f, 0.f}, psq[4] = {0.f, 0.f, 0.f, 0.f};
    #pragma unroll
    for (int ss = 0; ss < 4; ++ss) {
        int s = s0 + ss * 16 + m16;
        #pragma unroll
        for (int r = 0; r < 4; ++r) {
            float v = acc[ss][r] + bo[r];
            __bf16 vb = (__bf16)v;
            p[((size_t)n * C_ + c_base + r) * S_ + s] = vb;
            float vr = (float)vb;
            psum[r] += vr;
            psq[r]  += vr * vr;
        }
    }
    #pragma unroll
    for (int r = 0; r < 4; ++r) {
        #pragma unroll
        for (int off = 1; off < 16; off <<= 1) {
            psum[r] += __shfl_xor(psum[r], off);
            psq[r]  += __shfl_xor(psq[r], off);
        }
    }
    if (m16 == 0) {
        #pragma unroll
        for (int r = 0; r < 4; ++r) {
            atomicAdd(&ssum[c_base + r], psum[r]);
            atomicAdd(&ssq[c_base + r],  psq[r]);
        }
    }
}

// ---------------- small kernels ----------------
__global__ void zero_stats(float* ptr) {
    ptr[blockIdx.x * blockDim.x + threadIdx.x] = 0.0f;
}

__global__ void stats_kernel(const float* __restrict__ ssum, const float* __restrict__ ssq,
                             const float* __restrict__ gamma, const float* __restrict__ beta,
                             float* __restrict__ sc, float* __restrict__ sh)
{
    int c = threadIdx.x;  // 512
    const float inv_m = 1.0f / (float)((size_t)N_ * S_);
    float mean = ssum[c] * inv_m;
    float var = ssq[c] * inv_m - mean * mean;
    var = fmaxf(var, 0.0f);
    float inv = rsqrtf(var + EPS_);
    float g = gamma[c];
    sc[c] = inv * g;
    sh[c] = beta[c] - mean * inv * g;
}

__global__ __launch_bounds__(256) void apply_kernel(
    const float* __restrict__ x, const __bf16* __restrict__ p,
    const float* __restrict__ sc, const float* __restrict__ sh,
    float* __restrict__ out)
{
    size_t i4 = (size_t)blockIdx.x * blockDim.x + threadIdx.x;
    size_t base = i4 * 4;
    int c = (int)((base / S_) % C_);
    float4 xv = *(const float4*)(x + base);
    bf16x4 pv = *(const bf16x4*)(p + base);
    float s = sc[c], h = sh[c];
    float4 ov;
    ov.x = xv.x + (float)pv[0] * s + h;
    ov.y = xv.y + (float)pv[1] * s + h;
    ov.z = xv.z + (float)pv[2] * s + h;
    ov.w = xv.w + (float)pv[3] * s + h;
    *(float4*)(out + base) = ov;
}

extern "C" void kernel_launch(void* const* d_in, const int* in_sizes, int n_in,
                              void* d_out, int out_size, void* d_ws, size_t ws_size,
                              hipStream_t stream)
{
    const float* x       = (const float*)d_in[0];
    const float* w_theta = (const float*)d_in[1];
    const float* b_theta = (const float*)d_in[2];
    const float* w_phi   = (const float*)d_in[3];
    const float* b_phi   = (const float*)d_in[4];
    const float* w_g     = (const float*)d_in[5];
    const float* b_g     = (const float*)d_in[6];
    const float* w_out   = (const float*)d_in[7];
    const float* b_out   = (const float*)d_in[8];
    const float* gamma   = (const float*)d_in[9];
    const float* beta    = (const float*)d_in[10];

    char* ws = (char*)d_ws;
    const size_t sz_qkv = (size_t)N_ * S_ * CI_ * 2;  // 12,845,056 B
    __bf16* theta = (__bf16*)(ws);
    __bf16* phi   = (__bf16*)(ws + sz_qkv);
    __bf16* gT    = (__bf16*)(ws + 2 * sz_qkv);
    __bf16* O     = (__bf16*)(ws + 3 * sz_qkv);
    __bf16* p     = (__bf16*)(ws + 4 * sz_qkv);
    float* ssum   = (float*)(ws + 4 * sz_qkv + (size_t)N_ * C_ * S_ * 2);
    float* ssq = ssum + 512;
    float* scv = ssum + 1024;
    float* shv = ssum + 1536;

    zero_stats<<<1, 1024, 0, stream>>>(ssum);
    qkv_kernel<<<dim3(98, 4, 4), 256, 0, stream>>>(
        x, w_theta, b_theta, w_phi, b_phi, w_g, b_g, theta, phi, gT);
    attn_kernel<<<dim3(98, 4), 256, 0, stream>>>(theta, phi, gT, O);
    pgemm_kernel<<<dim3(98, 8, 4), 256, 0, stream>>>(O, w_out, b_out, p, ssum, ssq);
    stats_kernel<<<1, 512, 0, stream>>>(ssum, ssq, gamma, beta, scv, shv);
    apply_kernel<<<12544, 256, 0, stream>>>(x, p, scv, shv, (float*)d_out);
}

// Round 3
// 591.677 us; speedup vs baseline: 1.8150x; 1.8150x over previous
//
#include <hip/hip_runtime.h>
#include <hip/hip_bf16.h>

#define N_ 4
#define C_ 512
#define CI_ 256
#define S_ 6272
#define EPS_ 1e-5f
#define NKT 49        // key tiles (of 64) per split; 2 splits * 49 * 64 = 6272

typedef __attribute__((ext_vector_type(8))) __bf16 bf16x8;
typedef __attribute__((ext_vector_type(4))) __bf16 bf16x4;
typedef __attribute__((ext_vector_type(4))) float f32x4;

#define MFMA(a, b, c) __builtin_amdgcn_mfma_f32_16x16x32_bf16(a, b, c, 0, 0, 0)

__device__ __forceinline__ void gl_lds16(const void* g, void* l) {
    __builtin_amdgcn_global_load_lds(
        (const __attribute__((address_space(1))) void*)g,
        (__attribute__((address_space(3))) void*)l, 16, 0, 0);
}

// barrier that drains only LDS ops (leaves global_load_lds DMAs in flight)
#define BARRIER_LGKM() asm volatile("s_waitcnt lgkmcnt(0)\n\ts_barrier" ::: "memory")

// ---------------- Kernel 1: QKV projections ----------------
// M = ci (128/block), N = s (64/block), K = c.  Outputs:
//   theta[n][s][ci], phi[n][s][ci] (bf16)   gT[n][ci][s] (bf16)
__global__ __launch_bounds__(256) void qkv_kernel(
    const float* __restrict__ x,
    const float* __restrict__ w_theta, const float* __restrict__ b_theta,
    const float* __restrict__ w_phi,   const float* __restrict__ b_phi,
    const float* __restrict__ w_g,     const float* __restrict__ b_g,
    __bf16* __restrict__ theta, __bf16* __restrict__ phi, __bf16* __restrict__ gT)
{
    const int s0  = blockIdx.x * 64;
    const int ci0 = blockIdx.y * 128;
    const int n   = blockIdx.z;
    const int tid = threadIdx.x;
    const int wave = tid >> 6, lane = tid & 63;
    const int m16 = lane & 15, quad = lane >> 4;

    __shared__ __bf16 xT[64][40];  // [s-local][c-local(32)], pad->40

    const float* wptr[3] = {w_theta, w_phi, w_g};

    f32x4 acc[3][2][4];
    #pragma unroll
    for (int j = 0; j < 3; ++j)
        #pragma unroll
        for (int ct = 0; ct < 2; ++ct)
            #pragma unroll
            for (int ss = 0; ss < 4; ++ss) acc[j][ct][ss] = f32x4{0.f, 0.f, 0.f, 0.f};

    const int ci_row[2] = {ci0 + wave * 16 + m16, ci0 + 64 + wave * 16 + m16};

    for (int kc = 0; kc < 16; ++kc) {
        __syncthreads();
        // stage x[n][kc*32+c][s0..s0+64] -> xT[s][c]  (float4 along s)
        #pragma unroll
        for (int it = 0; it < 2; ++it) {
            int c_loc = it * 16 + (tid >> 4);
            int s4 = (tid & 15) * 4;
            float4 v = *(const float4*)&x[((size_t)n * C_ + kc * 32 + c_loc) * S_ + s0 + s4];
            xT[s4 + 0][c_loc] = (__bf16)v.x;
            xT[s4 + 1][c_loc] = (__bf16)v.y;
            xT[s4 + 2][c_loc] = (__bf16)v.z;
            xT[s4 + 3][c_loc] = (__bf16)v.w;
        }
        __syncthreads();

        bf16x8 afr[3][2];
        #pragma unroll
        for (int j = 0; j < 3; ++j)
            #pragma unroll
            for (int ct = 0; ct < 2; ++ct) {
                const float* wp = wptr[j] + (size_t)ci_row[ct] * C_ + kc * 32 + quad * 8;
                float4 wa = *(const float4*)wp;
                float4 wb = *(const float4*)(wp + 4);
                bf16x8 t;
                t[0] = (__bf16)wa.x; t[1] = (__bf16)wa.y; t[2] = (__bf16)wa.z; t[3] = (__bf16)wa.w;
                t[4] = (__bf16)wb.x; t[5] = (__bf16)wb.y; t[6] = (__bf16)wb.z; t[7] = (__bf16)wb.w;
                afr[j][ct] = t;
            }
        #pragma unroll
        for (int ss = 0; ss < 4; ++ss) {
            bf16x8 bfr = *(const bf16x8*)&xT[ss * 16 + m16][quad * 8];
            #pragma unroll
            for (int j = 0; j < 3; ++j)
                #pragma unroll
                for (int ct = 0; ct < 2; ++ct)
                    acc[j][ct][ss] = MFMA(afr[j][ct], bfr, acc[j][ct][ss]);
        }
    }

    #pragma unroll
    for (int ct = 0; ct < 2; ++ct) {
        const int ci_base = ci0 + ct * 64 + wave * 16 + quad * 4;
        float bth[4], bph[4], bgg[4];
        #pragma unroll
        for (int r = 0; r < 4; ++r) {
            bth[r] = b_theta[ci_base + r];
            bph[r] = b_phi[ci_base + r];
            bgg[r] = b_g[ci_base + r];
        }
        #pragma unroll
        for (int ss = 0; ss < 4; ++ss) {
            int s = s0 + ss * 16 + m16;
            bf16x4 tv, pv;
            #pragma unroll
            for (int r = 0; r < 4; ++r) {
                tv[r] = (__bf16)(acc[0][ct][ss][r] + bth[r]);
                pv[r] = (__bf16)(acc[1][ct][ss][r] + bph[r]);
            }
            *(bf16x4*)&theta[((size_t)n * S_ + s) * CI_ + ci_base] = tv;
            *(bf16x4*)&phi[((size_t)n * S_ + s) * CI_ + ci_base]   = pv;
            #pragma unroll
            for (int r = 0; r < 4; ++r)
                gT[((size_t)n * CI_ + ci_base + r) * S_ + s] = (__bf16)(acc[2][ct][ss][r] + bgg[r]);
        }
    }
}

// ---------------- Kernel 2: flash attention (self-staged LDS + DMA, split-K) ----------------
// Block: 64 queries, 4 waves; split handles 49 key tiles of 64.
// Wave w stages AND reads only its own K rows (keys w*16..+16) and V rows (ci w*64..+64);
// the only cross-wave LDS is p_lds.  XOR swizzle (chunk ^= row&7) on unpadded tiles
// gives even bank distribution; DMA staging via global_load_lds (16B).
// No max-subtraction softmax (scores bounded); outputs unnormalized O + l partials.
__global__ __launch_bounds__(256, 2) void attn_kernel(
    const __bf16* __restrict__ theta, const __bf16* __restrict__ phi,
    const __bf16* __restrict__ gT, __bf16* __restrict__ Opart, float* __restrict__ lpart)
{
    const int q0 = blockIdx.x * 64;
    const int split = blockIdx.y;
    const int n  = blockIdx.z;
    const int tid = threadIdx.x;
    const int w = tid >> 6, lane = tid & 63;
    const int m16 = lane & 15, quad = lane >> 4;
    const int xr = m16 & 7;

    extern __shared__ char smem[];
    __bf16* k_lds = (__bf16*)smem;                  // [64][256] swizzled
    __bf16* v_lds = (__bf16*)(smem + 32768);        // [256][64] swizzled
    __bf16* p_lds = (__bf16*)(smem + 65536);        // [64][72]
    float*  lsum  = (float*)(smem + 74752);         // [64][4]

    // ---- Q B-frags, register resident (128 VGPR) ----
    bf16x8 qreg[4][8];
    #pragma unroll
    for (int qf = 0; qf < 4; ++qf) {
        const __bf16* qrow = theta + ((size_t)n * S_ + q0 + qf * 16 + m16) * CI_ + quad * 8;
        #pragma unroll
        for (int kk = 0; kk < 8; ++kk)
            qreg[qf][kk] = *(const bf16x8*)(qrow + kk * 32);
    }

    // ---- staging bases ----
    // K: DMA j covers rows w*16+j*2 .. +2 (this wave's own keys).
    const int krow_loc = lane >> 5;                 // 0..1
    const int kA = (lane & 31) ^ krow_loc;          // jst ^ bit0(row)
    const char* kgbase = (const char*)(phi + ((size_t)n * S_ + (size_t)split * 3136 + w * 16) * CI_)
                         + krow_loc * 512;
    char* klbase = (char*)k_lds + w * 8192;
    // V: DMA j covers rows w*64+j*8 .. +8 (this wave's own ci rows).
    const int vrow_loc = lane >> 3;                 // 0..7
    const int vjsrc = (lane & 7) ^ vrow_loc;
    const char* vgbase = (const char*)gT + (((size_t)n * CI_ + w * 64 + vrow_loc) * S_
                         + (size_t)split * 3136) * 2 + vjsrc * 16;
    char* vlbase = (char*)v_lds + w * 8192;

    #define STAGE_K(kt_) { \
        const char* gk = kgbase + ((size_t)(kt_) << 15); \
        _Pragma("unroll") \
        for (int j = 0; j < 8; ++j) { \
            int jsrc = kA ^ ((2 * j) & 7); \
            gl_lds16(gk + j * 1024 + jsrc * 16, klbase + j * 1024); \
        } }
    #define STAGE_V2(kt_, j0_) { \
        const char* gv = vgbase + (size_t)(kt_) * 128; \
        gl_lds16(gv + (size_t)(j0_) * 100352, vlbase + (j0_) * 1024); \
        gl_lds16(gv + (size_t)((j0_) + 1) * 100352, vlbase + ((j0_) + 1) * 1024); }

    f32x4 o[4][4];  // [c][qf] -> o[ci = w*64+c*16+quad*4+r][q = qf*16+m16]
    #pragma unroll
    for (int c = 0; c < 4; ++c)
        #pragma unroll
        for (int qf = 0; qf < 4; ++qf) o[c][qf] = f32x4{0.f, 0.f, 0.f, 0.f};
    float l_part[4] = {0.f, 0.f, 0.f, 0.f};

    const __bf16* krow_ptr = k_lds + (w * 16 + m16) * 256;   // lane's own key row
    const __bf16* vrow_ptr = v_lds + (w * 64 + m16) * 64;    // + c*1024 per c-subtile

    STAGE_K(0);
    STAGE_V2(0, 0); STAGE_V2(0, 2); STAGE_V2(0, 4); STAGE_V2(0, 6);

    for (int kt = 0; kt < NKT; ++kt) {
        __syncthreads();   // drains own vmcnt (K/V staged); p_lds WAR vs prev PV

        // ---- QK^T: D[m=key(own 16)][n=q 64] ----
        f32x4 sc[4];
        #pragma unroll
        for (int qf = 0; qf < 4; ++qf) sc[qf] = f32x4{0.f, 0.f, 0.f, 0.f};
        #pragma unroll
        for (int kk = 0; kk < 8; ++kk) {
            bf16x8 kf = *(const bf16x8*)(krow_ptr + (((kk * 4 + quad) ^ xr) << 3));
            #pragma unroll
            for (int qf = 0; qf < 4; ++qf)
                sc[qf] = MFMA(kf, qreg[qf][kk], sc[qf]);
        }

        if (kt + 1 < NKT) STAGE_K(kt + 1);   // own k rows free; DMA rides through lgkm barrier

        // ---- exp (no max shift), accumulate l, P -> LDS [q][key] ----
        #pragma unroll
        for (int qf = 0; qf < 4; ++qf) {
            bf16x4 pk;
            float ls = 0.f;
            #pragma unroll
            for (int r = 0; r < 4; ++r) {
                float e = __expf(sc[qf][r] * 0.0625f);
                ls += e;
                pk[r] = (__bf16)e;
            }
            l_part[qf] += ls;
            *(bf16x4*)&p_lds[(qf * 16 + m16) * 72 + w * 16 + quad * 4] = pk;
        }
        BARRIER_LGKM();   // p visible; K-DMA stays in flight

        // ---- PV: D[m=ci(own 64)][n=q 64], V staging interleaved ----
        bf16x8 pf[4][2];
        #pragma unroll
        for (int qf = 0; qf < 4; ++qf)
            #pragma unroll
            for (int kk2 = 0; kk2 < 2; ++kk2)
                pf[qf][kk2] = *(const bf16x8*)&p_lds[(qf * 16 + m16) * 72 + kk2 * 32 + quad * 8];
        #pragma unroll
        for (int c = 0; c < 4; ++c) {
            #pragma unroll
            for (int kk2 = 0; kk2 < 2; ++kk2) {
                bf16x8 vf = *(const bf16x8*)(vrow_ptr + c * 1024 + (((kk2 * 4 + quad) ^ xr) << 3));
                #pragma unroll
                for (int qf = 0; qf < 4; ++qf)
                    o[c][qf] = MFMA(vf, pf[qf][kk2], o[c][qf]);
            }
            if (kt + 1 < NKT) STAGE_V2(kt + 1, 2 * c);   // rows c*16..+16 just freed
        }
    }

    // ---- cross-wave l reduction (per split, unnormalized) ----
    #pragma unroll
    for (int qf = 0; qf < 4; ++qf) {
        float l = l_part[qf];
        l += __shfl_xor(l, 16);
        l += __shfl_xor(l, 32);
        if (quad == 0) lsum[(qf * 16 + m16) * 4 + w] = l;
    }
    __syncthreads();
    if (tid < 64) {
        f32x4 lv = *(const f32x4*)&lsum[tid * 4];
        lpart[((size_t)split * N_ + n) * S_ + q0 + tid] = lv[0] + lv[1] + lv[2] + lv[3];
    }

    // ---- store unnormalized O partial ----
    __bf16* Op = Opart + (size_t)split * N_ * S_ * CI_;
    #pragma unroll
    for (int c = 0; c < 4; ++c)
        #pragma unroll
        for (int qf = 0; qf < 4; ++qf) {
            bf16x4 ov;
            #pragma unroll
            for (int r = 0; r < 4; ++r) ov[r] = (__bf16)o[c][qf][r];
            *(bf16x4*)&Op[((size_t)n * S_ + q0 + qf * 16 + m16) * CI_ + w * 64 + c * 16 + quad * 4] = ov;
        }
}

// ---------------- Kernel 3: w_out GEMM + fused split-combine + BN partial stats ----------------
__global__ __launch_bounds__(256) void pgemm_kernel(
    const __bf16* __restrict__ Opart, const float* __restrict__ lpart,
    const float* __restrict__ w_out, const float* __restrict__ b_out,
    __bf16* __restrict__ p, float* __restrict__ ssum, float* __restrict__ ssq)
{
    const int s0 = blockIdx.x * 64;
    const int c0 = blockIdx.y * 128;
    const int n  = blockIdx.z;
    const int tid = threadIdx.x;
    const int wave = tid >> 6, lane = tid & 63;
    const int m16 = lane & 15, quad = lane >> 4;

    __shared__ __bf16 o_lds[64][264];

    const __bf16* O0 = Opart;
    const __bf16* O1 = Opart + (size_t)N_ * S_ * CI_;
    #pragma unroll
    for (int it = 0; it < 8; ++it) {
        int idx = it * 256 + tid;
        int row = idx >> 5, ch = idx & 31;
        size_t ns = (size_t)n * S_ + s0 + row;
        float li = 1.0f / (lpart[ns] + lpart[(size_t)N_ * S_ + ns]);
        bf16x8 a = *(const bf16x8*)&O0[ns * CI_ + ch * 8];
        bf16x8 b = *(const bf16x8*)&O1[ns * CI_ + ch * 8];
        bf16x8 t;
        #pragma unroll
        for (int e = 0; e < 8; ++e) t[e] = (__bf16)(((float)a[e] + (float)b[e]) * li);
        *(bf16x8*)&o_lds[row][ch * 8] = t;
    }
    __syncthreads();

    #pragma unroll
    for (int ct = 0; ct < 2; ++ct) {
        const int c_row = c0 + ct * 64 + wave * 16 + m16;
        bf16x8 af[8];
        #pragma unroll
        for (int kk = 0; kk < 8; ++kk) {
            const float* wp = w_out + (size_t)c_row * CI_ + kk * 32 + quad * 8;
            float4 wa = *(const float4*)wp;
            float4 wb = *(const float4*)(wp + 4);
            bf16x8 t;
            t[0] = (__bf16)wa.x; t[1] = (__bf16)wa.y; t[2] = (__bf16)wa.z; t[3] = (__bf16)wa.w;
            t[4] = (__bf16)wb.x; t[5] = (__bf16)wb.y; t[6] = (__bf16)wb.z; t[7] = (__bf16)wb.w;
            af[kk] = t;
        }
        f32x4 acc[4];
        #pragma unroll
        for (int ss = 0; ss < 4; ++ss) acc[ss] = f32x4{0.f, 0.f, 0.f, 0.f};
        #pragma unroll
        for (int ss = 0; ss < 4; ++ss)
            #pragma unroll
            for (int kk = 0; kk < 8; ++kk) {
                bf16x8 bfr = *(const bf16x8*)&o_lds[ss * 16 + m16][kk * 32 + quad * 8];
                acc[ss] = MFMA(af[kk], bfr, acc[ss]);
            }

        const int c_base = c0 + ct * 64 + wave * 16 + quad * 4;
        float bo[4];
        #pragma unroll
        for (int r = 0; r < 4; ++r) bo[r] = b_out[c_base + r];
        float psum[4] = {0.f, 0.f, 0.f, 0.f}, psq[4] = {0.f, 0.f, 0.f, 0.f};
        #pragma unroll
        for (int ss = 0; ss < 4; ++ss) {
            int s = s0 + ss * 16 + m16;
            #pragma unroll
            for (int r = 0; r < 4; ++r) {
                float v = acc[ss][r] + bo[r];
                __bf16 vb = (__bf16)v;
                p[((size_t)n * C_ + c_base + r) * S_ + s] = vb;
                float vr = (float)vb;
                psum[r] += vr;
                psq[r]  += vr * vr;
            }
        }
        #pragma unroll
        for (int r = 0; r < 4; ++r) {
            #pragma unroll
            for (int off = 1; off < 16; off <<= 1) {
                psum[r] += __shfl_xor(psum[r], off);
                psq[r]  += __shfl_xor(psq[r], off);
            }
        }
        if (m16 == 0) {
            #pragma unroll
            for (int r = 0; r < 4; ++r) {
                atomicAdd(&ssum[c_base + r], psum[r]);
                atomicAdd(&ssq[c_base + r],  psq[r]);
            }
        }
    }
}

// ---------------- small kernels ----------------
__global__ void zero_stats(float* ptr) {
    ptr[blockIdx.x * blockDim.x + threadIdx.x] = 0.0f;
}

__global__ void stats_kernel(const float* __restrict__ ssum, const float* __restrict__ ssq,
                             const float* __restrict__ gamma, const float* __restrict__ beta,
                             float* __restrict__ sc, float* __restrict__ sh)
{
    int c = threadIdx.x;  // 512
    const float inv_m = 1.0f / (float)((size_t)N_ * S_);
    float mean = ssum[c] * inv_m;
    float var = ssq[c] * inv_m - mean * mean;
    var = fmaxf(var, 0.0f);
    float inv = rsqrtf(var + EPS_);
    float g = gamma[c];
    sc[c] = inv * g;
    sh[c] = beta[c] - mean * inv * g;
}

__global__ __launch_bounds__(256) void apply_kernel(
    const float* __restrict__ x, const __bf16* __restrict__ p,
    const float* __restrict__ sc, const float* __restrict__ sh,
    float* __restrict__ out)
{
    size_t i4 = (size_t)blockIdx.x * blockDim.x + threadIdx.x;
    size_t base = i4 * 4;
    int c = (int)((base / S_) % C_);
    float4 xv = *(const float4*)(x + base);
    bf16x4 pv = *(const bf16x4*)(p + base);
    float s = sc[c], h = sh[c];
    float4 ov;
    ov.x = xv.x + (float)pv[0] * s + h;
    ov.y = xv.y + (float)pv[1] * s + h;
    ov.z = xv.z + (float)pv[2] * s + h;
    ov.w = xv.w + (float)pv[3] * s + h;
    *(float4*)(out + base) = ov;
}

extern "C" void kernel_launch(void* const* d_in, const int* in_sizes, int n_in,
                              void* d_out, int out_size, void* d_ws, size_t ws_size,
                              hipStream_t stream)
{
    const float* x       = (const float*)d_in[0];
    const float* w_theta = (const float*)d_in[1];
    const float* b_theta = (const float*)d_in[2];
    const float* w_phi   = (const float*)d_in[3];
    const float* b_phi   = (const float*)d_in[4];
    const float* w_g     = (const float*)d_in[5];
    const float* b_g     = (const float*)d_in[6];
    const float* w_out   = (const float*)d_in[7];
    const float* b_out   = (const float*)d_in[8];
    const float* gamma   = (const float*)d_in[9];
    const float* beta    = (const float*)d_in[10];

    char* ws = (char*)d_ws;
    const size_t sz1 = (size_t)N_ * S_ * CI_ * 2;   // 12,845,056 B
    __bf16* theta = (__bf16*)(ws);
    __bf16* phi   = (__bf16*)(ws + sz1);
    __bf16* gT    = (__bf16*)(ws + 2 * sz1);
    __bf16* Opart = (__bf16*)(ws + 3 * sz1);        // 2 splits, 2*sz1
    __bf16* p     = (__bf16*)(ws);                  // overlays theta+phi (dead after attn)
    float* lpart  = (float*)(ws + 5 * sz1);         // 2*N*S floats = 200,704 B
    float* ssum   = (float*)(ws + 5 * sz1 + 2 * (size_t)N_ * S_ * sizeof(float));
    float* ssq = ssum + 512;
    float* scv = ssum + 1024;
    float* shv = ssum + 1536;

    zero_stats<<<1, 1024, 0, stream>>>(ssum);
    qkv_kernel<<<dim3(98, 2, 4), 256, 0, stream>>>(
        x, w_theta, b_theta, w_phi, b_phi, w_g, b_g, theta, phi, gT);
    hipFuncSetAttribute((const void*)attn_kernel,
                        hipFuncAttributeMaxDynamicSharedMemorySize, 75776);
    attn_kernel<<<dim3(98, 2, 4), 256, 75776, stream>>>(theta, phi, gT, Opart, lpart);
    pgemm_kernel<<<dim3(98, 4, 4), 256, 0, stream>>>(Opart, lpart, w_out, b_out, p, ssum, ssq);
    stats_kernel<<<1, 512, 0, stream>>>(ssum, ssq, gamma, beta, scv, shv);
    apply_kernel<<<12544, 256, 0, stream>>>(x, p, scv, shv, (float*)d_out);
}

// Round 5
// 523.309 us; speedup vs baseline: 2.0521x; 1.1306x over previous
//
#include <hip/hip_runtime.h>
#include <hip/hip_bf16.h>

#define N_ 4
#define C_ 512
#define CI_ 256
#define S_ 6272
#define EPS_ 1e-5f
#define NKT 49        // key tiles (of 64) per split; 2 splits * 49 * 64 = 6272

typedef __attribute__((ext_vector_type(8))) __bf16 bf16x8;
typedef __attribute__((ext_vector_type(4))) __bf16 bf16x4;
typedef __attribute__((ext_vector_type(4))) float f32x4;

#define MFMA(a, b, c) __builtin_amdgcn_mfma_f32_16x16x32_bf16(a, b, c, 0, 0, 0)

__device__ __forceinline__ void gl_lds16(const void* g, void* l) {
    __builtin_amdgcn_global_load_lds(
        (const __attribute__((address_space(1))) void*)g,
        (__attribute__((address_space(3))) void*)l, 16, 0, 0);
}

// barrier that drains only LDS ops (leaves global_load_lds DMAs in flight)
#define BARRIER_LGKM() asm volatile("s_waitcnt lgkmcnt(0)\n\ts_barrier" ::: "memory")
// order-only fence: my LDS reads are in registers before anything after this issues
#define FENCE_LGKM()   asm volatile("s_waitcnt lgkmcnt(0)" ::: "memory")

// ---------------- Kernel 1: QKV projections ----------------
// M = ci (128/block), N = s (64/block), K = c.  Outputs:
//   theta[n][s][ci], phi[n][s][ci] (bf16, PRE-SCALED by 0.25 each; exact since
//   0.25 is a power of two -> theta.phi = scores * ci^-0.5 directly)
//   gT[n][ci][s] (bf16)
__global__ __launch_bounds__(256) void qkv_kernel(
    const float* __restrict__ x,
    const float* __restrict__ w_theta, const float* __restrict__ b_theta,
    const float* __restrict__ w_phi,   const float* __restrict__ b_phi,
    const float* __restrict__ w_g,     const float* __restrict__ b_g,
    __bf16* __restrict__ theta, __bf16* __restrict__ phi, __bf16* __restrict__ gT)
{
    const int s0  = blockIdx.x * 64;
    const int ci0 = blockIdx.y * 128;
    const int n   = blockIdx.z;
    const int tid = threadIdx.x;
    const int wave = tid >> 6, lane = tid & 63;
    const int m16 = lane & 15, quad = lane >> 4;

    __shared__ __bf16 xT[64][40];  // [s-local][c-local(32)], pad->40

    const float* wptr[3] = {w_theta, w_phi, w_g};

    f32x4 acc[3][2][4];
    #pragma unroll
    for (int j = 0; j < 3; ++j)
        #pragma unroll
        for (int ct = 0; ct < 2; ++ct)
            #pragma unroll
            for (int ss = 0; ss < 4; ++ss) acc[j][ct][ss] = f32x4{0.f, 0.f, 0.f, 0.f};

    const int ci_row[2] = {ci0 + wave * 16 + m16, ci0 + 64 + wave * 16 + m16};

    for (int kc = 0; kc < 16; ++kc) {
        __syncthreads();
        // stage x[n][kc*32+c][s0..s0+64] -> xT[s][c]  (float4 along s)
        #pragma unroll
        for (int it = 0; it < 2; ++it) {
            int c_loc = it * 16 + (tid >> 4);
            int s4 = (tid & 15) * 4;
            float4 v = *(const float4*)&x[((size_t)n * C_ + kc * 32 + c_loc) * S_ + s0 + s4];
            xT[s4 + 0][c_loc] = (__bf16)v.x;
            xT[s4 + 1][c_loc] = (__bf16)v.y;
            xT[s4 + 2][c_loc] = (__bf16)v.z;
            xT[s4 + 3][c_loc] = (__bf16)v.w;
        }
        __syncthreads();

        bf16x8 afr[3][2];
        #pragma unroll
        for (int j = 0; j < 3; ++j)
            #pragma unroll
            for (int ct = 0; ct < 2; ++ct) {
                const float* wp = wptr[j] + (size_t)ci_row[ct] * C_ + kc * 32 + quad * 8;
                float4 wa = *(const float4*)wp;
                float4 wb = *(const float4*)(wp + 4);
                bf16x8 t;
                t[0] = (__bf16)wa.x; t[1] = (__bf16)wa.y; t[2] = (__bf16)wa.z; t[3] = (__bf16)wa.w;
                t[4] = (__bf16)wb.x; t[5] = (__bf16)wb.y; t[6] = (__bf16)wb.z; t[7] = (__bf16)wb.w;
                afr[j][ct] = t;
            }
        #pragma unroll
        for (int ss = 0; ss < 4; ++ss) {
            bf16x8 bfr = *(const bf16x8*)&xT[ss * 16 + m16][quad * 8];
            #pragma unroll
            for (int j = 0; j < 3; ++j)
                #pragma unroll
                for (int ct = 0; ct < 2; ++ct)
                    acc[j][ct][ss] = MFMA(afr[j][ct], bfr, acc[j][ct][ss]);
        }
    }

    #pragma unroll
    for (int ct = 0; ct < 2; ++ct) {
        const int ci_base = ci0 + ct * 64 + wave * 16 + quad * 4;
        float bth[4], bph[4], bgg[4];
        #pragma unroll
        for (int r = 0; r < 4; ++r) {
            bth[r] = b_theta[ci_base + r];
            bph[r] = b_phi[ci_base + r];
            bgg[r] = b_g[ci_base + r];
        }
        #pragma unroll
        for (int ss = 0; ss < 4; ++ss) {
            int s = s0 + ss * 16 + m16;
            bf16x4 tv, pv;
            #pragma unroll
            for (int r = 0; r < 4; ++r) {
                tv[r] = (__bf16)((acc[0][ct][ss][r] + bth[r]) * 0.25f);
                pv[r] = (__bf16)((acc[1][ct][ss][r] + bph[r]) * 0.25f);
            }
            *(bf16x4*)&theta[((size_t)n * S_ + s) * CI_ + ci_base] = tv;
            *(bf16x4*)&phi[((size_t)n * S_ + s) * CI_ + ci_base]   = pv;
            #pragma unroll
            for (int r = 0; r < 4; ++r)
                gT[((size_t)n * CI_ + ci_base + r) * S_ + s] = (__bf16)(acc[2][ct][ss][r] + bgg[r]);
        }
    }
}

// ---------------- Kernel 2: flash attention ----------------
// Block: 64 queries, 4 waves; split handles 49 key tiles of 64.
// QK: wave = (q-half h=w&1, key-half kh=w>>1): 32x32 score quadrant.
//     Each kf b128 feeds 2 MFMAs (1:2 read:MFMA).  qreg = 64 VGPR (no remat).
// PV: wave w owns ci [64w,+64), all 64 q; V rows self-staged/self-read.
// RACE FIX (R4 failure): every V-prefetch DMA preceded by FENCE_LGKM so the
// wave's own vf ds_reads are in registers before the DMA overwrites the rows.
// K-prefetch after mid-barrier (all waves' kf reads provably drained there).
// No max-subtraction softmax; outputs unnormalized O + l partials.
__global__ __launch_bounds__(256, 2) void attn_kernel(
    const __bf16* __restrict__ theta, const __bf16* __restrict__ phi,
    const __bf16* __restrict__ gT, __bf16* __restrict__ Opart, float* __restrict__ lpart)
{
    const int q0 = blockIdx.x * 64;
    const int split = blockIdx.y;
    const int n  = blockIdx.z;
    const int tid = threadIdx.x;
    const int w = tid >> 6, lane = tid & 63;
    const int m16 = lane & 15, quad = lane >> 4;
    const int xr = m16 & 7;
    const int h = w & 1, kh = w >> 1;

    extern __shared__ char smem[];
    __bf16* k_lds = (__bf16*)smem;                  // [64][256] swizzled
    __bf16* v_lds = (__bf16*)(smem + 32768);        // [256][64] swizzled
    __bf16* p_lds = (__bf16*)(smem + 65536);        // [64][72]  (9216 B)
    float*  lsum  = (float*)(smem + 74752);         // [64][2]   (512 B)

    // ---- Q B-frags: this wave's 32 queries (q-half h) -> 64 VGPR ----
    bf16x8 qreg[2][8];
    #pragma unroll
    for (int qf = 0; qf < 2; ++qf) {
        const __bf16* qrow = theta + ((size_t)n * S_ + q0 + h * 32 + qf * 16 + m16) * CI_ + quad * 8;
        #pragma unroll
        for (int kk = 0; kk < 8; ++kk) qreg[qf][kk] = *(const bf16x8*)(qrow + kk * 32);
    }

    // ---- staging bases (wave w stages K rows [w*16,+16), V rows [w*64,+64)) ----
    const int krow_loc = lane >> 5;                 // 0..1
    const int kA = (lane & 31) ^ krow_loc;
    const char* kgbase = (const char*)(phi + ((size_t)n * S_ + (size_t)split * 3136 + w * 16) * CI_)
                         + krow_loc * 512;
    char* klbase = (char*)k_lds + w * 8192;
    const int vrow_loc = lane >> 3;                 // 0..7
    const int vjsrc = (lane & 7) ^ vrow_loc;
    const char* vgbase = (const char*)gT + (((size_t)n * CI_ + w * 64 + vrow_loc) * S_
                         + (size_t)split * 3136) * 2 + vjsrc * 16;
    char* vlbase = (char*)v_lds + w * 8192;

    #define STAGE_K(kt_) { \
        const char* gk = kgbase + ((size_t)(kt_) << 15); \
        _Pragma("unroll") \
        for (int j = 0; j < 8; ++j) { \
            int jsrc = kA ^ ((2 * j) & 7); \
            gl_lds16(gk + j * 1024 + jsrc * 16, klbase + j * 1024); \
        } }
    #define STAGE_V2(kt_, j0_) { \
        const char* gv = vgbase + (size_t)(kt_) * 128; \
        gl_lds16(gv + (size_t)(j0_) * 100352, vlbase + (j0_) * 1024); \
        gl_lds16(gv + (size_t)((j0_) + 1) * 100352, vlbase + ((j0_) + 1) * 1024); }

    f32x4 o[4][4];  // [c][qf] -> o[ci = w*64+c*16+quad*4+r][q = qf*16+m16]
    #pragma unroll
    for (int c = 0; c < 4; ++c)
        #pragma unroll
        for (int qf = 0; qf < 4; ++qf) o[c][qf] = f32x4{0.f, 0.f, 0.f, 0.f};
    float l_part[2] = {0.f, 0.f};

    const __bf16* vrow_ptr = v_lds + (w * 64 + m16) * 64;    // + c*1024 per c-subtile

    STAGE_K(0);
    STAGE_V2(0, 0); STAGE_V2(0, 2); STAGE_V2(0, 4); STAGE_V2(0, 6);

    for (int kt = 0; kt < NKT; ++kt) {
        __syncthreads();   // drains own vmcnt -> all K/V staged & visible; p_lds WAR

        // ---- QK^T quadrant: D[m = key kh*32+sub*16+..][n = q-half h, qf*16+m16] ----
        f32x4 sc[2][2];
        #pragma unroll
        for (int sub = 0; sub < 2; ++sub)
            #pragma unroll
            for (int qf = 0; qf < 2; ++qf) sc[sub][qf] = f32x4{0.f, 0.f, 0.f, 0.f};
        #pragma unroll
        for (int kk = 0; kk < 8; ++kk) {
            #pragma unroll
            for (int sub = 0; sub < 2; ++sub) {
                bf16x8 kf = *(const bf16x8*)&k_lds[(kh * 32 + sub * 16 + m16) * 256
                                                   + (((kk * 4 + quad) ^ xr) << 3)];
                #pragma unroll
                for (int qf = 0; qf < 2; ++qf)
                    sc[sub][qf] = MFMA(kf, qreg[qf][kk], sc[sub][qf]);
            }
        }

        // ---- exp (pre-scaled scores, no max shift), l accum, P -> LDS [q][key] ----
        #pragma unroll
        for (int sub = 0; sub < 2; ++sub)
            #pragma unroll
            for (int qf = 0; qf < 2; ++qf) {
                bf16x4 pk;
                float ls = 0.f;
                #pragma unroll
                for (int r = 0; r < 4; ++r) {
                    float e = __expf(sc[sub][qf][r]);
                    ls += e;
                    pk[r] = (__bf16)e;
                }
                l_part[qf] += ls;
                *(bf16x4*)&p_lds[(h * 32 + qf * 16 + m16) * 72 + kh * 32 + sub * 16 + quad * 4] = pk;
            }
        BARRIER_LGKM();   // all P visible; all waves' kf reads drained -> K overwrite safe

        if (kt + 1 < NKT) STAGE_K(kt + 1);   // rides through PV, drains at next top barrier

        // ---- PV: D[m = ci(own 64)][n = q 64]; V prefetch fenced per half ----
        bf16x8 pf[4][2];
        #pragma unroll
        for (int qf = 0; qf < 4; ++qf)
            #pragma unroll
            for (int kk2 = 0; kk2 < 2; ++kk2)
                pf[qf][kk2] = *(const bf16x8*)&p_lds[(qf * 16 + m16) * 72 + kk2 * 32 + quad * 8];
        #pragma unroll
        for (int g = 0; g < 2; ++g) {
            bf16x8 vf[2][2];
            #pragma unroll
            for (int cc = 0; cc < 2; ++cc)
                #pragma unroll
                for (int kk2 = 0; kk2 < 2; ++kk2)
                    vf[cc][kk2] = *(const bf16x8*)(vrow_ptr + (g * 2 + cc) * 1024
                                                   + (((kk2 * 4 + quad) ^ xr) << 3));
            if (kt + 1 < NKT) {
                FENCE_LGKM();                 // vf (and pf) in registers -> safe to overwrite
                STAGE_V2(kt + 1, 4 * g);
                STAGE_V2(kt + 1, 4 * g + 2);
            }
            #pragma unroll
            for (int cc = 0; cc < 2; ++cc)
                #pragma unroll
                for (int kk2 = 0; kk2 < 2; ++kk2)
                    #pragma unroll
                    for (int qf = 0; qf < 4; ++qf)
                        o[g * 2 + cc][qf] = MFMA(vf[cc][kk2], pf[qf][kk2], o[g * 2 + cc][qf]);
        }
    }

    // ---- l: sum over quads (own 32 keys), then combine key-halves via LDS ----
    #pragma unroll
    for (int qf = 0; qf < 2; ++qf) {
        float l = l_part[qf];
        l += __shfl_xor(l, 16);
        l += __shfl_xor(l, 32);
        if (quad == 0) lsum[(h * 32 + qf * 16 + m16) * 2 + kh] = l;
    }
    __syncthreads();
    if (tid < 64)
        lpart[((size_t)split * N_ + n) * S_ + q0 + tid] = lsum[tid * 2] + lsum[tid * 2 + 1];

    // ---- store unnormalized O partial ----
    __bf16* Op = Opart + (size_t)split * N_ * S_ * CI_;
    #pragma unroll
    for (int c = 0; c < 4; ++c)
        #pragma unroll
        for (int qf = 0; qf < 4; ++qf) {
            bf16x4 ov;
            #pragma unroll
            for (int r = 0; r < 4; ++r) ov[r] = (__bf16)o[c][qf][r];
            *(bf16x4*)&Op[((size_t)n * S_ + q0 + qf * 16 + m16) * CI_ + w * 64 + c * 16 + quad * 4] = ov;
        }
}

// ---------------- Kernel 3: w_out GEMM + fused split-combine + BN partial stats ----------------
__global__ __launch_bounds__(256) void pgemm_kernel(
    const __bf16* __restrict__ Opart, const float* __restrict__ lpart,
    const float* __restrict__ w_out, const float* __restrict__ b_out,
    __bf16* __restrict__ p, float* __restrict__ ssum, float* __restrict__ ssq)
{
    const int s0 = blockIdx.x * 64;
    const int c0 = blockIdx.y * 128;
    const int n  = blockIdx.z;
    const int tid = threadIdx.x;
    const int wave = tid >> 6, lane = tid & 63;
    const int m16 = lane & 15, quad = lane >> 4;

    __shared__ __bf16 o_lds[64][264];

    const __bf16* O0 = Opart;
    const __bf16* O1 = Opart + (size_t)N_ * S_ * CI_;
    #pragma unroll
    for (int it = 0; it < 8; ++it) {
        int idx = it * 256 + tid;
        int row = idx >> 5, ch = idx & 31;
        size_t ns = (size_t)n * S_ + s0 + row;
        float li = 1.0f / (lpart[ns] + lpart[(size_t)N_ * S_ + ns]);
        bf16x8 a = *(const bf16x8*)&O0[ns * CI_ + ch * 8];
        bf16x8 b = *(const bf16x8*)&O1[ns * CI_ + ch * 8];
        bf16x8 t;
        #pragma unroll
        for (int e = 0; e < 8; ++e) t[e] = (__bf16)(((float)a[e] + (float)b[e]) * li);
        *(bf16x8*)&o_lds[row][ch * 8] = t;
    }
    __syncthreads();

    #pragma unroll
    for (int ct = 0; ct < 2; ++ct) {
        const int c_row = c0 + ct * 64 + wave * 16 + m16;
        bf16x8 af[8];
        #pragma unroll
        for (int kk = 0; kk < 8; ++kk) {
            const float* wp = w_out + (size_t)c_row * CI_ + kk * 32 + quad * 8;
            float4 wa = *(const float4*)wp;
            float4 wb = *(const float4*)(wp + 4);
            bf16x8 t;
            t[0] = (__bf16)wa.x; t[1] = (__bf16)wa.y; t[2] = (__bf16)wa.z; t[3] = (__bf16)wa.w;
            t[4] = (__bf16)wb.x; t[5] = (__bf16)wb.y; t[6] = (__bf16)wb.z; t[7] = (__bf16)wb.w;
            af[kk] = t;
        }
        f32x4 acc[4];
        #pragma unroll
        for (int ss = 0; ss < 4; ++ss) acc[ss] = f32x4{0.f, 0.f, 0.f, 0.f};
        #pragma unroll
        for (int ss = 0; ss < 4; ++ss)
            #pragma unroll
            for (int kk = 0; kk < 8; ++kk) {
                bf16x8 bfr = *(const bf16x8*)&o_lds[ss * 16 + m16][kk * 32 + quad * 8];
                acc[ss] = MFMA(af[kk], bfr, acc[ss]);
            }

        const int c_base = c0 + ct * 64 + wave * 16 + quad * 4;
        float bo[4];
        #pragma unroll
        for (int r = 0; r < 4; ++r) bo[r] = b_out[c_base + r];
        float psum[4] = {0.f, 0.f, 0.f, 0.f}, psq[4] = {0.f, 0.f, 0.f, 0.f};
        #pragma unroll
        for (int ss = 0; ss < 4; ++ss) {
            int s = s0 + ss * 16 + m16;
            #pragma unroll
            for (int r = 0; r < 4; ++r) {
                float v = acc[ss][r] + bo[r];
                __bf16 vb = (__bf16)v;
                p[((size_t)n * C_ + c_base + r) * S_ + s] = vb;
                float vr = (float)vb;
                psum[r] += vr;
                psq[r]  += vr * vr;
            }
        }
        #pragma unroll
        for (int r = 0; r < 4; ++r) {
            #pragma unroll
            for (int off = 1; off < 16; off <<= 1) {
                psum[r] += __shfl_xor(psum[r], off);
                psq[r]  += __shfl_xor(psq[r], off);
            }
        }
        if (m16 == 0) {
            #pragma unroll
            for (int r = 0; r < 4; ++r) {
                atomicAdd(&ssum[c_base + r], psum[r]);
                atomicAdd(&ssq[c_base + r],  psq[r]);
            }
        }
    }
}

// ---------------- small kernels ----------------
__global__ void zero_stats(float* ptr) {
    ptr[blockIdx.x * blockDim.x + threadIdx.x] = 0.0f;
}

__global__ void stats_kernel(const float* __restrict__ ssum, const float* __restrict__ ssq,
                             const float* __restrict__ gamma, const float* __restrict__ beta,
                             float* __restrict__ sc, float* __restrict__ sh)
{
    int c = threadIdx.x;  // 512
    const float inv_m = 1.0f / (float)((size_t)N_ * S_);
    float mean = ssum[c] * inv_m;
    float var = ssq[c] * inv_m - mean * mean;
    var = fmaxf(var, 0.0f);
    float inv = rsqrtf(var + EPS_);
    float g = gamma[c];
    sc[c] = inv * g;
    sh[c] = beta[c] - mean * inv * g;
}

__global__ __launch_bounds__(256) void apply_kernel(
    const float* __restrict__ x, const __bf16* __restrict__ p,
    const float* __restrict__ sc, const float* __restrict__ sh,
    float* __restrict__ out)
{
    size_t i4 = (size_t)blockIdx.x * blockDim.x + threadIdx.x;
    size_t base = i4 * 4;
    int c = (int)((base / S_) % C_);
    float4 xv = *(const float4*)(x + base);
    bf16x4 pv = *(const bf16x4*)(p + base);
    float s = sc[c], h = sh[c];
    float4 ov;
    ov.x = xv.x + (float)pv[0] * s + h;
    ov.y = xv.y + (float)pv[1] * s + h;
    ov.z = xv.z + (float)pv[2] * s + h;
    ov.w = xv.w + (float)pv[3] * s + h;
    *(float4*)(out + base) = ov;
}

extern "C" void kernel_launch(void* const* d_in, const int* in_sizes, int n_in,
                              void* d_out, int out_size, void* d_ws, size_t ws_size,
                              hipStream_t stream)
{
    const float* x       = (const float*)d_in[0];
    const float* w_theta = (const float*)d_in[1];
    const float* b_theta = (const float*)d_in[2];
    const float* w_phi   = (const float*)d_in[3];
    const float* b_phi   = (const float*)d_in[4];
    const float* w_g     = (const float*)d_in[5];
    const float* b_g     = (const float*)d_in[6];
    const float* w_out   = (const float*)d_in[7];
    const float* b_out   = (const float*)d_in[8];
    const float* gamma   = (const float*)d_in[9];
    const float* beta    = (const float*)d_in[10];

    char* ws = (char*)d_ws;
    const size_t sz1 = (size_t)N_ * S_ * CI_ * 2;   // 12,845,056 B
    __bf16* theta = (__bf16*)(ws);
    __bf16* phi   = (__bf16*)(ws + sz1);
    __bf16* gT    = (__bf16*)(ws + 2 * sz1);
    __bf16* Opart = (__bf16*)(ws + 3 * sz1);        // 2 splits, 2*sz1
    __bf16* p     = (__bf16*)(ws);                  // overlays theta+phi (dead after attn)
    float* lpart  = (float*)(ws + 5 * sz1);         // 2*N*S floats = 200,704 B
    float* ssum   = (float*)(ws + 5 * sz1 + 2 * (size_t)N_ * S_ * sizeof(float));
    float* ssq = ssum + 512;
    float* scv = ssum + 1024;
    float* shv = ssum + 1536;

    zero_stats<<<1, 1024, 0, stream>>>(ssum);
    qkv_kernel<<<dim3(98, 2, 4), 256, 0, stream>>>(
        x, w_theta, b_theta, w_phi, b_phi, w_g, b_g, theta, phi, gT);
    hipFuncSetAttribute((const void*)attn_kernel,
                        hipFuncAttributeMaxDynamicSharedMemorySize, 75776);
    attn_kernel<<<dim3(98, 2, 4), 256, 75776, stream>>>(theta, phi, gT, Opart, lpart);
    pgemm_kernel<<<dim3(98, 4, 4), 256, 0, stream>>>(Opart, lpart, w_out, b_out, p, ssum, ssq);
    stats_kernel<<<1, 512, 0, stream>>>(ssum, ssq, gamma, beta, scv, shv);
    apply_kernel<<<12544, 256, 0, stream>>>(x, p, scv, shv, (float*)d_out);
}